// Round 2
// baseline (141.140 us; speedup 1.0000x reference)
//
#include <hip/hip_runtime.h>

// QuantLinear: out[8,11008] = x[8,4096] @ W[11008,4096]^T
// packed[i] (INT32, one per byte!) holds 2 nibbles: low = weight 2i, high = weight 2i+1;
// weight = (q-8)*scale[idx/32]. 2048 int32 per row of 4096 k.
//
// R10: kill the fill. R9's profile showed top-5 dispatches are ALL fillBufferAligned
//   (~55 us each); qlin_kernel absent from top-5 => < 54 us while dur_us=140.
//   The timed graph is fill-dominated. The only fill we own is the hipMemsetAsync
//   required by split-K atomicAdd. So: replace atomics with plain stores of split-K
//   partials into d_ws (8 x 88064 floats = 2.8 MB), then a tiny reduce kernel
//   (86 WGs, float4) sums the 8 partials -> out. No memset in the graph at all.
//   Compute core is byte-identical R9 (passed, <54us): split-K=8, 2 row-groups/WG
//   register-double-buffered, __launch_bounds__(256,4), 16 KB LDS x-tile.
//   Fallback: if ws_size < 2.8 MB, use the verified memset+atomic path.

#define OUT_F 11008
#define IN_F  4096
#define OUT_ELEMS (8 * OUT_F)                    // 88064

template<bool WS>
__device__ __forceinline__ void group_compute(
    const float* xs, const int2 (&wq)[2][4], const float (&sc)[2][4],
    int lane, int rbase, float* __restrict__ dst)
{
    float acc[32];                                // acc[r*8 + m]
#pragma unroll
    for (int i = 0; i < 32; ++i) acc[i] = 0.f;

#pragma unroll
    for (int t = 0; t < 2; ++t) {
        float w[4][4];
#pragma unroll
        for (int r = 0; r < 4; ++r) {
            const int   px = wq[t][r].x, py = wq[t][r].y;
            const float s  = sc[t][r];
            const float ns = -8.f * s;
            w[r][0] = fmaf((float)(px & 15), s, ns);   // k+0
            w[r][1] = fmaf((float)(px >> 4), s, ns);   // k+1 (byte < 256: no &15 needed)
            w[r][2] = fmaf((float)(py & 15), s, ns);   // k+2
            w[r][3] = fmaf((float)(py >> 4), s, ns);   // k+3
        }

        const int kl = t * 256 + lane * 4;             // local k in strip
#pragma unroll
        for (int m = 0; m < 8; ++m) {
            const float4 xa = *(const float4*)(xs + m * 512 + kl);  // ds_read_b128
#pragma unroll
            for (int r = 0; r < 4; ++r) {
                float a = acc[r * 8 + m];
                a = fmaf(w[r][0], xa.x, a);
                a = fmaf(w[r][1], xa.y, a);
                a = fmaf(w[r][2], xa.z, a);
                a = fmaf(w[r][3], xa.w, a);
                acc[r * 8 + m] = a;
            }
        }
    }

    // ---- merge tree over 32 values: lane l<32 ends with wave-total for index l ----
#pragma unroll
    for (int st = 0; st < 5; ++st) {
        const int bit = (lane >> st) & 1;
        const int n = 16 >> st;
#pragma unroll
        for (int jj = 0; jj < n; ++jj) {
            const float u = bit ? acc[2 * jj + 1] : acc[2 * jj];
            const float v = bit ? acc[2 * jj]     : acc[2 * jj + 1];
            acc[jj] = u + __shfl_xor(v, 1 << st, 64);
        }
    }
    acc[0] += __shfl_xor(acc[0], 32, 64);

    if (lane < 32) {
        const int r = lane >> 3;                       // index l = r*8 + m
        const int m = lane & 7;
        if (WS) dst[m * OUT_F + rbase + r] = acc[0];   // exclusive owner: plain store
        else    atomicAdd(dst + m * OUT_F + rbase + r, acc[0]);
    }
}

template<bool WS>
__global__ __launch_bounds__(256, 4) void qlin_kernel(
    const float* __restrict__ x,
    const int*   __restrict__ packed,
    const float* __restrict__ scales,
    float*       __restrict__ outw)
{
    const int tid  = threadIdx.x;
    const int lane = tid & 63;
    const int wave = tid >> 6;
    const int b    = blockIdx.x;
    const int e    = b & 7;                  // k-strip 0..7 (512 k each)
    const int j    = b >> 3;                 // row-group pair 0..343
    const int ke   = e << 9;                 // global k base of strip

    // WS path: each strip writes its own 88064-float partial slice
    float* dst = WS ? (outw + e * OUT_ELEMS) : outw;

    __shared__ float xs[8 * 512];            // 16 KB

    // ---- 1) x loads FIRST: oldest entries in the vmcnt queue ----
    float4 xv[4];
    {
        const float* xg = x + ke;
#pragma unroll
        for (int i = 0; i < 4; ++i) {
            const int f  = tid + (i << 8);        // float4 id 0..1023
            const int m  = f >> 7;
            const int kv = (f & 127) << 2;
            xv[i] = *(const float4*)(xg + m * IN_F + kv);
        }
    }

    // ---- 2) group-0 weight + scale loads (int32 units: lane*2 dwords = 4 k) ----
    const int g0   = j * 2;
    const int row0 = g0 * 16 + wave * 4;          // group-0 wave rows
    int2  wqA[2][4]; float scA[2][4];
    {
        const int pb = row0 * 2048 + (ke >> 1) + lane * 2;
        const int sb = row0 * 128  + (ke >> 5) + (lane >> 3);
#pragma unroll
        for (int t = 0; t < 2; ++t)
#pragma unroll
            for (int r = 0; r < 4; ++r) {
                wqA[t][r] = *(const int2*)(packed + pb + r * 2048 + t * 128);
                scA[t][r] = scales[sb + r * 128 + t * 8];
            }
    }

    // ---- 3) stage x (waits only the 4 oldest loads), barrier drains g0 loads ----
#pragma unroll
    for (int i = 0; i < 4; ++i) {
        const int f  = tid + (i << 8);
        const int m  = f >> 7;
        const int kv = (f & 127) << 2;
        *(float4*)(xs + m * 512 + kv) = xv[i];
    }
    __syncthreads();

    // ---- 4) group-1 loads: issued now, in flight across ALL of group-0 compute ----
    const int row1 = row0 + 16;
    int2  wqB[2][4]; float scB[2][4];
    {
        const int pb = row1 * 2048 + (ke >> 1) + lane * 2;
        const int sb = row1 * 128  + (ke >> 5) + (lane >> 3);
#pragma unroll
        for (int t = 0; t < 2; ++t)
#pragma unroll
            for (int r = 0; r < 4; ++r) {
                wqB[t][r] = *(const int2*)(packed + pb + r * 2048 + t * 128);
                scB[t][r] = scales[sb + r * 128 + t * 8];
            }
    }

    // ---- 5) compute: g0 (regs ready at barrier), then g1 (latency hidden) ----
    group_compute<WS>(xs, wqA, scA, lane, row0, dst);
    group_compute<WS>(xs, wqB, scB, lane, row1, dst);
}

// out[i] = sum_e ws[e][i], float4-vectorized. 22016 float4s = 86 WGs x 256 thr.
__global__ __launch_bounds__(256) void reduce_kernel(
    const float* __restrict__ ws, float* __restrict__ out)
{
    const int i = blockIdx.x * 256 + threadIdx.x;     // float4 index 0..22015
    const float4* w4 = (const float4*)ws;
    float4 s = w4[i];
#pragma unroll
    for (int e = 1; e < 8; ++e) {
        const float4 v = w4[e * (OUT_ELEMS / 4) + i];
        s.x += v.x; s.y += v.y; s.z += v.z; s.w += v.w;
    }
    ((float4*)out)[i] = s;
}

extern "C" void kernel_launch(void* const* d_in, const int* in_sizes, int n_in,
                              void* d_out, int out_size, void* d_ws, size_t ws_size,
                              hipStream_t stream) {
    const float* x      = (const float*)d_in[0];
    const int*   packed = (const int*)  d_in[1];
    const float* scales = (const float*)d_in[2];
    float*       out    = (float*)d_out;

    const size_t WS_NEED = (size_t)8 * OUT_ELEMS * sizeof(float);   // 2.8 MB
    dim3 grid((OUT_F / 32) * 8), block(256);          // 2752 WGs x 4 waves

    if (d_ws != nullptr && ws_size >= WS_NEED) {
        // no-memset path: split-K partials -> ws (plain stores), then reduce
        float* ws = (float*)d_ws;
        hipLaunchKernelGGL(qlin_kernel<true>, grid, block, 0, stream,
                           x, packed, scales, ws);
        hipLaunchKernelGGL(reduce_kernel, dim3(OUT_ELEMS / 4 / 256), block, 0, stream,
                           ws, out);
    } else {
        // fallback: verified memset + atomicAdd path
        hipMemsetAsync(out, 0, (size_t)out_size * sizeof(float), stream);
        hipLaunchKernelGGL(qlin_kernel<false>, grid, block, 0, stream,
                           x, packed, scales, out);
    }
}

// Round 3
// 141.072 us; speedup vs baseline: 1.0005x; 1.0005x over previous
//
#include <hip/hip_runtime.h>

// QuantLinear: out[8,11008] = x[8,4096] @ W[11008,4096]^T
// packed[i] (INT32, one per byte!) holds 2 nibbles: low = weight 2i, high = weight 2i+1;
// weight = (q-8)*scale[idx/32]. 2048 int32 per row of 4096 k.
//
// R11: int4 weight loads + conflict-free even/odd x layout.
//   Evidence: the ~53us fills are HARNESS re-poison (360.7 MB each; removing our memset
//   in R10 changed nothing). Window = 2 fills (~106us) + qlin(~30) + reduce(~4).
//   qlin runs at ~3.3 TB/s vs 6.3 achievable -> attack its VMEM instr count:
//   - lane owns 8 consecutive k: weights = one int4/row (16 B/lane, 1 KB/wave-instr,
//     coalescing sweet spot); one tile per 512-k strip. VMEM 36 -> 20 instrs/thread.
//   - x LDS even/odd split layout: block fk stored at slot (fk>>1)+(fk&1)*64, so the
//     lane's two b128 reads (k 8l..8l+3 and 8l+4..8l+7) are both stride-16B contiguous
//     across the wave (conflict-free); staging writes = 2 contiguous 512B runs/instr.
//   - structure otherwise R10: split-K=8, 2 row-groups/WG register-double-buffered,
//     __launch_bounds__(256,4), ws partials + reduce kernel (no memset in graph).

#define OUT_F 11008
#define IN_F  4096
#define OUT_ELEMS (8 * OUT_F)                    // 88064

template<bool WS>
__device__ __forceinline__ void group_compute(
    const float* xs, const int4 (&wq)[4], const float (&sc)[4],
    int lane, int rbase, float* __restrict__ dst)
{
    // ---- dequant: 4 rows x 8 k (lane's k = 8*lane .. 8*lane+7) ----
    float w[4][8];
#pragma unroll
    for (int r = 0; r < 4; ++r) {
        const int   pa = wq[r].x, pb = wq[r].y, pc = wq[r].z, pd = wq[r].w;
        const float s  = sc[r];
        const float ns = -8.f * s;
        w[r][0] = fmaf((float)(pa & 15), s, ns);   // k+0
        w[r][1] = fmaf((float)(pa >> 4), s, ns);   // k+1 (byte < 256: no &15)
        w[r][2] = fmaf((float)(pb & 15), s, ns);   // k+2
        w[r][3] = fmaf((float)(pb >> 4), s, ns);   // k+3
        w[r][4] = fmaf((float)(pc & 15), s, ns);   // k+4
        w[r][5] = fmaf((float)(pc >> 4), s, ns);   // k+5
        w[r][6] = fmaf((float)(pd & 15), s, ns);   // k+6
        w[r][7] = fmaf((float)(pd >> 4), s, ns);   // k+7
    }

    float acc[32];                                // acc[r*8 + m]
#pragma unroll
    for (int i = 0; i < 32; ++i) acc[i] = 0.f;

#pragma unroll
    for (int m = 0; m < 8; ++m) {
        // even/odd layout: slot l = original block 2l (k 8l..8l+3),
        //                  slot 64+l = block 2l+1 (k 8l+4..8l+7)
        const float4 xa = *(const float4*)(xs + m * 512 + lane * 4);
        const float4 xb = *(const float4*)(xs + m * 512 + 256 + lane * 4);
#pragma unroll
        for (int r = 0; r < 4; ++r) {
            float a = acc[r * 8 + m];
            a = fmaf(w[r][0], xa.x, a);
            a = fmaf(w[r][1], xa.y, a);
            a = fmaf(w[r][2], xa.z, a);
            a = fmaf(w[r][3], xa.w, a);
            a = fmaf(w[r][4], xb.x, a);
            a = fmaf(w[r][5], xb.y, a);
            a = fmaf(w[r][6], xb.z, a);
            a = fmaf(w[r][7], xb.w, a);
            acc[r * 8 + m] = a;
        }
    }

    // ---- merge tree over 32 values: lane l<32 ends with wave-total for index l ----
#pragma unroll
    for (int st = 0; st < 5; ++st) {
        const int bit = (lane >> st) & 1;
        const int n = 16 >> st;
#pragma unroll
        for (int jj = 0; jj < n; ++jj) {
            const float u = bit ? acc[2 * jj + 1] : acc[2 * jj];
            const float v = bit ? acc[2 * jj]     : acc[2 * jj + 1];
            acc[jj] = u + __shfl_xor(v, 1 << st, 64);
        }
    }
    acc[0] += __shfl_xor(acc[0], 32, 64);

    if (lane < 32) {
        const int r = lane >> 3;                       // index l = r*8 + m
        const int m = lane & 7;
        if (WS) dst[m * OUT_F + rbase + r] = acc[0];   // exclusive owner: plain store
        else    atomicAdd(dst + m * OUT_F + rbase + r, acc[0]);
    }
}

template<bool WS>
__global__ __launch_bounds__(256, 4) void qlin_kernel(
    const float* __restrict__ x,
    const int*   __restrict__ packed,
    const float* __restrict__ scales,
    float*       __restrict__ outw)
{
    const int tid  = threadIdx.x;
    const int lane = tid & 63;
    const int wave = tid >> 6;
    const int b    = blockIdx.x;
    const int e    = b & 7;                  // k-strip 0..7 (512 k each)
    const int j    = b >> 3;                 // row-group pair 0..343
    const int ke   = e << 9;                 // global k base of strip

    float* dst = WS ? (outw + e * OUT_ELEMS) : outw;

    __shared__ float xs[8 * 512];            // 16 KB

    // ---- 1) x loads FIRST: oldest entries in the vmcnt queue ----
    float4 xv[4];
    {
        const float* xg = x + ke;
#pragma unroll
        for (int i = 0; i < 4; ++i) {
            const int f  = tid + (i << 8);        // float4 block id 0..1023
            const int m  = f >> 7;
            const int fk = f & 127;
            xv[i] = *(const float4*)(xg + m * IN_F + fk * 4);
        }
    }

    // ---- 2) group-0 weight + scale loads (int4: lane*4 dwords = 8 k) ----
    const int row0 = j * 32 + wave * 4;           // group-0 wave rows
    int4  wqA[4]; float scA[4];
    {
        const int pb = row0 * 2048 + (ke >> 1) + lane * 4;  // int32 units
        const int sb = row0 * 128  + (ke >> 5) + (lane >> 2);
#pragma unroll
        for (int r = 0; r < 4; ++r) {
            wqA[r] = *(const int4*)(packed + pb + r * 2048);
            scA[r] = scales[sb + r * 128];
        }
    }

    // ---- 3) stage x permuted (even/odd split); waits only the 4 oldest loads ----
#pragma unroll
    for (int i = 0; i < 4; ++i) {
        const int f  = tid + (i << 8);
        const int m  = f >> 7;
        const int fk = f & 127;
        const int sl = (fk >> 1) + (fk & 1) * 64;  // even blocks -> 0..63, odd -> 64..127
        *(float4*)(xs + m * 512 + sl * 4) = xv[i];
    }
    __syncthreads();

    // ---- 4) group-1 loads: issued now, in flight across ALL of group-0 compute ----
    const int row1 = row0 + 16;
    int4  wqB[4]; float scB[4];
    {
        const int pb = row1 * 2048 + (ke >> 1) + lane * 4;
        const int sb = row1 * 128  + (ke >> 5) + (lane >> 2);
#pragma unroll
        for (int r = 0; r < 4; ++r) {
            wqB[r] = *(const int4*)(packed + pb + r * 2048);
            scB[r] = scales[sb + r * 128];
        }
    }

    // ---- 5) compute: g0 (regs ready at barrier), then g1 (latency hidden) ----
    group_compute<WS>(xs, wqA, scA, lane, row0, dst);
    group_compute<WS>(xs, wqB, scB, lane, row1, dst);
}

// out[i] = sum_e ws[e][i], float4-vectorized. 22016 float4s = 86 WGs x 256 thr.
__global__ __launch_bounds__(256) void reduce_kernel(
    const float* __restrict__ ws, float* __restrict__ out)
{
    const int i = blockIdx.x * 256 + threadIdx.x;     // float4 index 0..22015
    const float4* w4 = (const float4*)ws;
    float4 s = w4[i];
#pragma unroll
    for (int e = 1; e < 8; ++e) {
        const float4 v = w4[e * (OUT_ELEMS / 4) + i];
        s.x += v.x; s.y += v.y; s.z += v.z; s.w += v.w;
    }
    ((float4*)out)[i] = s;
}

extern "C" void kernel_launch(void* const* d_in, const int* in_sizes, int n_in,
                              void* d_out, int out_size, void* d_ws, size_t ws_size,
                              hipStream_t stream) {
    const float* x      = (const float*)d_in[0];
    const int*   packed = (const int*)  d_in[1];
    const float* scales = (const float*)d_in[2];
    float*       out    = (float*)d_out;

    const size_t WS_NEED = (size_t)8 * OUT_ELEMS * sizeof(float);   // 2.8 MB
    dim3 grid((OUT_F / 32) * 8), block(256);          // 2752 WGs x 4 waves

    if (d_ws != nullptr && ws_size >= WS_NEED) {
        // no-memset path: split-K partials -> ws (plain stores), then reduce
        float* ws = (float*)d_ws;
        hipLaunchKernelGGL(qlin_kernel<true>, grid, block, 0, stream,
                           x, packed, scales, ws);
        hipLaunchKernelGGL(reduce_kernel, dim3(OUT_ELEMS / 4 / 256), block, 0, stream,
                           ws, out);
    } else {
        // fallback: verified memset + atomicAdd path
        hipMemsetAsync(out, 0, (size_t)out_size * sizeof(float), stream);
        hipLaunchKernelGGL(qlin_kernel<false>, grid, block, 0, stream,
                           x, packed, scales, out);
    }
}

// Round 4
// 140.309 us; speedup vs baseline: 1.0059x; 1.0054x over previous
//
#include <hip/hip_runtime.h>

// QuantLinear: out[8,11008] = x[8,4096] @ W[11008,4096]^T
// packed[i] (INT32, one per byte!) holds 2 nibbles: low = weight 2i, high = weight 2i+1;
// weight = (q-8)*scale[idx/32]. 2048 int32 per row of 4096 k.
//
// R12: single dispatch, full-K per WG, 8-deep strip pipeline.
//   Evidence so far: window = 2 harness re-poison fills (~110us, 344 MiB each @6.5TB/s,
//   untouchable) + qlin (~25-28us vs 15.3us HBM floor) + reduce (~4us) + gaps.
//   R11's VMEM trims were noise => attack structure, not instructions:
//   - WG owns 8 rows x full K: acc[16] lives in registers across all 8 strips
//     -> plain stores. NO split-K, NO atomics, NO memset, NO ws, NO reduce dispatch.
//   - 2-phase pipeline per strip: issue strip e+1 loads (4x float4 x + 2x int4 wt)
//     BEFORE strip e's FMAs; ds_write + one barrier per strip. After the prologue,
//     HBM latency always hides under compute (T3-minimum pattern).
//   - x LDS even/odd split layout (R11): both b128 reads stride-16B conflict-free.
//   Grid: 1376 WGs x 256 thr (5.4/CU). LDS 2x16KB. VGPR est ~90 -> (256,4) no spill.
//   Wave = 2 rows; lane owns 8 consecutive k per strip (int4 weight = 16B/lane).

#define OUT_F 11008
#define IN_F  4096

__global__ __launch_bounds__(256, 4) void qlin_kernel(
    const float* __restrict__ x,
    const int*   __restrict__ packed,
    const float* __restrict__ scales,
    float*       __restrict__ out)
{
    const int tid  = threadIdx.x;
    const int lane = tid & 63;
    const int wave = tid >> 6;
    const int row0 = blockIdx.x * 8 + wave * 2;     // wave's 2 rows

    __shared__ float xs[2][8 * 512];                // 32 KB: double-buffered x strip

    // weight/scale bases (int32 / float units); strip e adds e*256 / e*16
    const int pb0 = row0 * 2048 + lane * 4;
    const int sb0 = row0 * 128 + (lane >> 2);

    // ---- prologue: strip-0 x loads (oldest in queue), strip-0 weight loads ----
    float4 xv[4];
#pragma unroll
    for (int i = 0; i < 4; ++i) {
        const int f = tid + (i << 8), m = f >> 7, fk = f & 127;   // f: float4 id 0..1023
        xv[i] = *(const float4*)(x + m * IN_F + fk * 4);
    }
    int4 wqC[2]; float scC[2];
#pragma unroll
    for (int r = 0; r < 2; ++r) {
        wqC[r] = *(const int4*)(packed + pb0 + r * 2048);
        scC[r] = scales[sb0 + r * 128];
    }
    // stage strip 0 permuted: even blocks -> slots 0..63, odd -> 64..127 (conflict-free b128)
#pragma unroll
    for (int i = 0; i < 4; ++i) {
        const int f = tid + (i << 8), m = f >> 7, fk = f & 127;
        const int sl = (fk >> 1) + ((fk & 1) << 6);
        *(float4*)(&xs[0][m * 512 + sl * 4]) = xv[i];
    }
    __syncthreads();

    float acc[16];                                   // acc[r*8 + m]
#pragma unroll
    for (int i = 0; i < 16; ++i) acc[i] = 0.f;

#pragma unroll
    for (int e = 0; e < 8; ++e) {
        const int cur = e & 1;

        // ---- prefetch strip e+1 into registers (in flight across this strip's FMAs) ----
        int4 wqN[2]; float scN[2];
        if (e < 7) {
#pragma unroll
            for (int i = 0; i < 4; ++i) {
                const int f = tid + (i << 8), m = f >> 7, fk = f & 127;
                xv[i] = *(const float4*)(x + (e + 1) * 512 + m * IN_F + fk * 4);
            }
#pragma unroll
            for (int r = 0; r < 2; ++r) {
                wqN[r] = *(const int4*)(packed + pb0 + (e + 1) * 256 + r * 2048);
                scN[r] = scales[sb0 + (e + 1) * 16 + r * 128];
            }
        }

        // ---- dequant current weights: 2 rows x 8 k (lane's k = e*512 + 8*lane ..) ----
        float w[2][8];
#pragma unroll
        for (int r = 0; r < 2; ++r) {
            const int   pa = wqC[r].x, pb = wqC[r].y, pc = wqC[r].z, pd = wqC[r].w;
            const float s  = scC[r];
            const float ns = -8.f * s;
            w[r][0] = fmaf((float)(pa & 15), s, ns);   // k+0
            w[r][1] = fmaf((float)(pa >> 4), s, ns);   // k+1 (byte < 256: no &15)
            w[r][2] = fmaf((float)(pb & 15), s, ns);   // k+2
            w[r][3] = fmaf((float)(pb >> 4), s, ns);   // k+3
            w[r][4] = fmaf((float)(pc & 15), s, ns);   // k+4
            w[r][5] = fmaf((float)(pc >> 4), s, ns);   // k+5
            w[r][6] = fmaf((float)(pd & 15), s, ns);   // k+6
            w[r][7] = fmaf((float)(pd >> 4), s, ns);   // k+7
        }

        // ---- FMAs over 8 batch rows ----
#pragma unroll
        for (int m = 0; m < 8; ++m) {
            const float4 xa = *(const float4*)(&xs[cur][m * 512 + lane * 4]);
            const float4 xb = *(const float4*)(&xs[cur][m * 512 + 256 + lane * 4]);
#pragma unroll
            for (int r = 0; r < 2; ++r) {
                float a = acc[r * 8 + m];
                a = fmaf(w[r][0], xa.x, a);
                a = fmaf(w[r][1], xa.y, a);
                a = fmaf(w[r][2], xa.z, a);
                a = fmaf(w[r][3], xa.w, a);
                a = fmaf(w[r][4], xb.x, a);
                a = fmaf(w[r][5], xb.y, a);
                a = fmaf(w[r][6], xb.z, a);
                a = fmaf(w[r][7], xb.w, a);
                acc[r * 8 + m] = a;
            }
        }

        // ---- stage strip e+1 into the other buffer; one barrier per strip ----
        if (e < 7) {
#pragma unroll
            for (int i = 0; i < 4; ++i) {
                const int f = tid + (i << 8), m = f >> 7, fk = f & 127;
                const int sl = (fk >> 1) + ((fk & 1) << 6);
                *(float4*)(&xs[cur ^ 1][m * 512 + sl * 4]) = xv[i];   // waits xv vmcnt
            }
            wqC[0] = wqN[0]; wqC[1] = wqN[1];
            scC[0] = scN[0]; scC[1] = scN[1];
            __syncthreads();   // RAW for next strip's reads + WAR for the write after it
        }
    }

    // ---- merge tree over 16 values: lane l ends with wave-total for index l&15 ----
#pragma unroll
    for (int st = 0; st < 4; ++st) {
        const int bit = (lane >> st) & 1;
        const int n = 8 >> st;
#pragma unroll
        for (int jj = 0; jj < n; ++jj) {
            const float u = bit ? acc[2 * jj + 1] : acc[2 * jj];
            const float v = bit ? acc[2 * jj]     : acc[2 * jj + 1];
            acc[jj] = u + __shfl_xor(v, 1 << st, 64);
        }
    }
    acc[0] += __shfl_xor(acc[0], 16, 64);
    acc[0] += __shfl_xor(acc[0], 32, 64);

    if (lane < 16) {
        const int r = lane >> 3;                     // index l = r*8 + m
        const int m = lane & 7;
        out[m * OUT_F + row0 + r] = acc[0];          // exclusive owner: plain store
    }
}

extern "C" void kernel_launch(void* const* d_in, const int* in_sizes, int n_in,
                              void* d_out, int out_size, void* d_ws, size_t ws_size,
                              hipStream_t stream) {
    const float* x      = (const float*)d_in[0];
    const int*   packed = (const int*)  d_in[1];
    const float* scales = (const float*)d_in[2];
    float*       out    = (float*)d_out;

    // single dispatch: full-K accumulation in registers, plain stores
    hipLaunchKernelGGL(qlin_kernel, dim3(OUT_F / 8), dim3(256), 0, stream,
                       x, packed, scales, out);
}